// Round 7
// baseline (262.857 us; speedup 1.0000x reference)
//
#include <hip/hip_runtime.h>
#include <hip/hip_cooperative_groups.h>

namespace cg = cooperative_groups;

#define K_ 9
#define SIGMA_INV 12.5f
#define EPS 1e-5f
#define B_ 4
#define C_ 64
#define O_ 64
#define N_ 16384
#define RCAP 128      // per-region correction-entry capacity (256 regions)

typedef __attribute__((ext_vector_type(8))) short short8;
typedef __attribute__((ext_vector_type(4))) float f32x4;

__device__ __forceinline__ unsigned short f2bf(float f) {
    union { float f; unsigned u; } v; v.f = f;
    unsigned r = v.u + 0x7fffu + ((v.u >> 16) & 1u);   // round-nearest-even
    return (unsigned short)(r >> 16);
}
__device__ __forceinline__ float bf2f(unsigned short h) {
    union { unsigned u; float f; } v; v.u = ((unsigned)h) << 16;
    return v.f;
}
__device__ __forceinline__ void gload16(const void* g, void* l) {
    __builtin_amdgcn_global_load_lds((const __attribute__((address_space(1))) unsigned int*)g,
                                     (__attribute__((address_space(3))) unsigned int*)l,
                                     16, 0, 0);
}

// ---------------------------------------------------------------------------
// K_setup: heterogeneous roles, one launch.
//  [0,1024)      : transpose+bf16-convert tile (64n x 64c)
//  [1024,1280)   : scan (region-compacted via LDS atomic; flag/bcnt written
//                  unconditionally -> zero memsets needed)
//  [1280,1324)   : prep (4x M->Mfrag, 36x Wt, 4x FWt)
//  [1324,1580)   : chain: h[i][b][n] = composed-gather(reidx), pointer-chase
// ---------------------------------------------------------------------------
__global__ __launch_bounds__(256) void k_setup(
    const float* __restrict__ in, const float* __restrict__ mc,
    const int* __restrict__ indices, const int* __restrict__ reidx,
    const float* __restrict__ cw, const float* __restrict__ fw,
    unsigned short* __restrict__ xtb, int* __restrict__ h,
    unsigned short* __restrict__ Mfrag, float* __restrict__ Wt,
    float* __restrict__ FWt,
    int* __restrict__ flag, int* __restrict__ emeta,
    float* __restrict__ ed, int* __restrict__ bcnt)
{
    int bid = blockIdx.x, t = threadIdx.x;
    if (bid < 1024) {                                    // ---- transpose + cvt
        __shared__ float tile[64][65];
        int b = bid & 3, n0 = (bid >> 2) * 64;
        for (int rep = 0; rep < 16; ++rep) {
            int idx = rep * 256 + t;
            int c = idx >> 6, j = idx & 63;
            tile[c][j] = in[((size_t)b * C_ + c) * N_ + n0 + j];
        }
        __syncthreads();
        for (int rep = 0; rep < 4; ++rep) {              // ushort4 packed writes
            int idx = rep * 256 + t;
            int j = idx >> 4, c4 = (idx & 15) * 4;
            ushort4 o;
            o.x = f2bf(tile[c4 + 0][j]); o.y = f2bf(tile[c4 + 1][j]);
            o.z = f2bf(tile[c4 + 2][j]); o.w = f2bf(tile[c4 + 3][j]);
            *(ushort4*)&xtb[((size_t)b * N_ + n0 + j) * 64 + c4] = o;
        }
    } else if (bid < 1280) {                             // ---- scan
        __shared__ float cs[3][264][4];
        __shared__ int lcnt;
        int sb = bid - 1024;                             // region id
        int b = sb & 3, n0 = (sb >> 2) * 256;
        if (t == 0) lcnt = 0;
        for (int idx = t; idx < 3 * 264; idx += 256) {
            int a = idx / 264, r = idx - a * 264;
            int m = n0 + r - 4;
            f32x4 v;
            if (m >= 0 && m < N_) v = *(const f32x4*)&mc[(((size_t)b * 3 + a) * N_ + m) * 4];
            else { v[0] = 1e9f; v[1] = 1e9f; v[2] = 1e9f; v[3] = 1e9f; }
            *(f32x4*)&cs[a][r][0] = v;
        }
        __syncthreads();
        int p = n0 + t;
        for (int i = 0; i < 4; ++i) {
            float c0 = cs[0][t + 4][i], c1 = cs[1][t + 4][i], c2 = cs[2][t + 4][i];
            float d[8]; bool any = false;
            #pragma unroll
            for (int kk = 0; kk < 8; ++kk) {
                int k = kk + (kk >= 4);
                float d0 = cs[0][t + k][i] - c0, d1 = cs[1][t + k][i] - c1,
                      d2 = cs[2][t + k][i] - c2;
                float dist = sqrtf(d0 * d0 + d1 * d1 + d2 * d2);
                float dd = 1.f - dist * SIGMA_INV;
                d[kk] = dd > 0.f ? dd : 0.f;
                any = any || (dd > 0.f);
            }
            int fv = 0;
            if (any) {
                int li = atomicAdd(&lcnt, 1);            // LDS atomic: no global init
                if (li < RCAP) {
                    int slot = sb * RCAP + li;
                    emeta[slot] = (i << 14) | p;
                    #pragma unroll
                    for (int kk = 0; kk < 8; ++kk) ed[(size_t)slot * 8 + kk] = d[kk];
                    fv = slot + 1;
                }
            }
            flag[(size_t)(i * 4 + b) * N_ + p] = fv;     // unconditional
        }
        __syncthreads();
        if (t == 0) bcnt[sb] = lcnt < RCAP ? lcnt : RCAP;
    } else if (bid < 1324) {                             // ---- prep
        int pb = bid - 1280;
        if (pb < 4) {
            __shared__ float w4[64][65];
            __shared__ float fws[64][65];
            int i = pb;
            for (int idx = t; idx < 4096; idx += 256) {
                int op = idx >> 6, c = idx & 63;
                w4[op][c]  = cw[(((size_t)(i * 64 + op)) * 64 + c) * 9 + 4];
                fws[op][c] = fw[(size_t)op * 256 + i * 64 + c];
            }
            __syncthreads();
            int o = t >> 2, cb = (t & 3) * 16;
            float acc[16];
            #pragma unroll
            for (int j = 0; j < 16; ++j) acc[j] = 0.f;
            for (int op = 0; op < 64; ++op) {
                float f = fws[o][op];
                #pragma unroll
                for (int j = 0; j < 16; ++j) acc[j] += f * w4[op][cb + j];
            }
            // MFMA A-fragment layout: Mfrag[w][s][lane][8]
            #pragma unroll
            for (int j = 0; j < 16; ++j) {
                int c = cb + j;
                int s = i * 2 + (c >> 5);
                int l = (((c >> 3) & 3) << 4) | (o & 15);
                int w_ = o >> 4;
                Mfrag[(((size_t)w_ * 8 + s) * 64 + l) * 8 + (c & 7)] = f2bf(acc[j]);
            }
        } else if (pb < 40) {
            int idx2 = pb - 4;
            int i = idx2 / 9, k = idx2 - i * 9;
            for (int idx = t; idx < 4096; idx += 256) {
                int c = idx >> 6, o = idx & 63;
                Wt[(size_t)(i * 9 + k) * 4096 + c * 64 + o] =
                    cw[(((size_t)(i * 64 + o)) * 64 + c) * 9 + k];
            }
        } else {
            int i = pb - 40;
            for (int idx = t; idx < 4096; idx += 256) {
                int c = idx >> 6, o = idx & 63;
                FWt[(size_t)(i * 64 + c) * 64 + o] = fw[(size_t)o * 256 + i * 64 + c];
            }
        }
    } else {                                             // ---- chain
        int gid = (bid - 1324) * 256 + t;                // over B*N
        int b = gid >> 14, n = gid & (N_ - 1);
        const int* ib = indices + (size_t)b * N_ * 4;
        const int4 r = *(const int4*)&reidx[((size_t)b * N_ + n) * 4];
        int t0 = ib[(size_t)r.x * 4 + 0];
        int t1 = ib[(size_t)r.y * 4 + 1];
        int t2 = ib[(size_t)r.z * 4 + 2];
        int t3 = ib[(size_t)r.w * 4 + 3];
        t1 = ib[(size_t)t1 * 4 + 0];
        t2 = ib[(size_t)t2 * 4 + 1];
        t3 = ib[(size_t)t3 * 4 + 2];
        t2 = ib[(size_t)t2 * 4 + 0];
        t3 = ib[(size_t)t3 * 4 + 1];
        t3 = ib[(size_t)t3 * 4 + 0];
        h[(size_t)(0 * 4 + b) * N_ + n] = t0;
        h[(size_t)(1 * 4 + b) * N_ + n] = t1;
        h[(size_t)(2 * 4 + b) * N_ + n] = t2;
        h[(size_t)(3 * 4 + b) * N_ + n] = t3;
    }
}

// corrections: region-sliced; wave (bid&7) of region (bid>>3) handles entries
// li = wir, wir+8, ... ; tap rows pointer-chased in parallel lanes.
__global__ __launch_bounds__(64) void k_corr(
    const unsigned short* __restrict__ xtb, const int* __restrict__ indices,
    const float* __restrict__ Wt, const float* __restrict__ FWt,
    const int* __restrict__ emeta, const float* __restrict__ ed,
    const int* __restrict__ bcnt, float* __restrict__ zcorr)
{
    __shared__ float xls[8][64];
    __shared__ float ycs[64];
    __shared__ int rows_s[8];
    int t = threadIdx.x;
    int r = blockIdx.x >> 3, wir = blockIdx.x & 7;
    int b = r & 3;
    int cr = bcnt[r];
    const int* idxb = indices + (size_t)b * N_ * 4;
    for (int li = wir; li < cr; li += 8) {
        int slot = r * RCAP + li;
        int meta = emeta[slot];
        int i = meta >> 14, p = meta & 16383;
        float dd[8];
        #pragma unroll
        for (int kk = 0; kk < 8; ++kk) dd[kk] = ed[(size_t)slot * 8 + kk];
        if (t < 8) {                         // lane t chases tap t's row
            int row = 0;
            if (dd[t] > 0.f) {
                int k = t + (t >= 4);
                int rr = p + k - 4;          // in-bounds guaranteed when dd>0
                for (int s = i; s >= 0; --s) rr = idxb[(size_t)rr * 4 + s];
                row = rr;
            }
            rows_s[t] = row;
        }
        __syncthreads();
        #pragma unroll
        for (int kk = 0; kk < 8; ++kk) {
            if (dd[kk] > 0.f)
                xls[kk][t] = bf2f(xtb[((size_t)b * N_ + rows_s[kk]) * 64 + t]);
        }
        __syncthreads();
        float y = 0.f;
        #pragma unroll 1
        for (int kk = 0; kk < 8; ++kk) {
            if (dd[kk] > 0.f) {
                int k = kk + (kk >= 4);
                const float* w = Wt + (size_t)(i * 9 + k) * 4096;
                float s0 = 0.f, s1 = 0.f, s2 = 0.f, s3 = 0.f;
                #pragma unroll
                for (int c = 0; c < 64; c += 4) {
                    s0 += w[(c + 0) * 64 + t] * xls[kk][c + 0];
                    s1 += w[(c + 1) * 64 + t] * xls[kk][c + 1];
                    s2 += w[(c + 2) * 64 + t] * xls[kk][c + 2];
                    s3 += w[(c + 3) * 64 + t] * xls[kk][c + 3];
                }
                y += dd[kk] * (((s0 + s1) + (s2 + s3)));
            }
        }
        ycs[t] = y;
        __syncthreads();
        const float* fwt = FWt + (size_t)i * 4096;
        float v0 = 0.f, v1 = 0.f, v2 = 0.f, v3 = 0.f;
        #pragma unroll
        for (int c = 0; c < 64; c += 4) {
            v0 += fwt[(c + 0) * 64 + t] * ycs[c + 0];
            v1 += fwt[(c + 1) * 64 + t] * ycs[c + 1];
            v2 += fwt[(c + 2) * 64 + t] * ycs[c + 2];
            v3 += fwt[(c + 3) * 64 + t] * ycs[c + 3];
        }
        zcorr[(size_t)slot * 64 + t] = (v0 + v1) + (v2 + v3);
        __syncthreads();
    }
}

// ---------------------------------------------------------------------------
// k_mega2 (cooperative, 512 blocks = 2 blocks/CU, wide safety margin):
// each block owns TWO adjacent n-tiles of one batch; both tiles' gathers
// issued up-front (16 gload_lds in flight/wave); z stays in registers across
// two grid syncs; phase2 reduces pstats (stride 512); phase3 applies BN+ReLU.
// ---------------------------------------------------------------------------
__global__ __launch_bounds__(256, 2) void k_mega2(
    const unsigned short* __restrict__ xtb, const int* __restrict__ h,
    const int* __restrict__ flag, const int* __restrict__ reidx,
    const unsigned short* __restrict__ Mfrag, const float* __restrict__ zcorr,
    const float* __restrict__ fb, const float* __restrict__ gamma,
    const float* __restrict__ beta, float* __restrict__ pstats,
    float* __restrict__ sc, float* __restrict__ out)
{
    __shared__ __align__(16) unsigned short xg[2][256 * 64];   // 64KB, chunk-swizzled
    __shared__ int fs[2][256];
    __shared__ float red_s[4], red_q[4];
    int bid = blockIdx.x;
    int b = bid & 3;                               // batch (XCD pairs by bid%8)
    int base = (bid >> 2) * 128;                   // two tiles: base, base+64
    int t = threadIdx.x;
    int lane = t & 63, w = t >> 6;

    // ---- phase 1: both tiles ----
    short8 af[8];
    #pragma unroll
    for (int s = 0; s < 8; ++s)
        af[s] = *(const short8*)&Mfrag[(((size_t)w * 8 + s) * 64 + lane) * 8];
    #pragma unroll
    for (int j = 0; j < 2; ++j) {
        int n0 = base + j * 64;
        int hvv[8];
        #pragma unroll
        for (int it = 0; it < 8; ++it)
            hvv[it] = h[(size_t)(w * 4 + b) * N_ + n0 + it * 8 + (lane >> 3)];
        #pragma unroll
        for (int it = 0; it < 8; ++it) {
            int p = it * 8 + (lane >> 3);
            int cg = (lane & 7) ^ (p & 7);         // source-chunk swizzle
            const unsigned short* gp = xtb + ((size_t)b * N_ + hvv[it]) * 64 + cg * 8;
            gload16(gp, &xg[j][(size_t)(w * 64 + it * 8) * 64]);
        }
        {   // correction flags, overlapped with gather latency
            int i = t >> 6, p = t & 63;
            int pr = reidx[((size_t)b * N_ + n0 + p) * 4 + i];
            fs[j][t] = flag[(size_t)(i * 4 + b) * N_ + pr];
        }
    }
    asm volatile("s_waitcnt vmcnt(0)" ::: "memory");
    __syncthreads();

    f32x4 acc[2][4];
    #pragma unroll
    for (int j = 0; j < 2; ++j)
        #pragma unroll
        for (int ct = 0; ct < 4; ++ct) { acc[j][ct][0]=0.f; acc[j][ct][1]=0.f; acc[j][ct][2]=0.f; acc[j][ct][3]=0.f; }
    #pragma unroll
    for (int j = 0; j < 2; ++j)
        #pragma unroll
        for (int s = 0; s < 8; ++s) {
            int i2 = s >> 1;
            int cg = (s & 1) * 4 + (lane >> 4);
            #pragma unroll
            for (int ct = 0; ct < 4; ++ct) {
                int pos = ct * 16 + (lane & 15);
                const short8 bf = *(const short8*)((const char*)&xg[j][0] +
                    ((size_t)(i2 * 64 + pos) * 128) + ((cg ^ (pos & 7)) * 16));
                acc[j][ct] = __builtin_amdgcn_mfma_f32_16x16x32_bf16(af[s], bf, acc[j][ct], 0, 0, 0);
            }
        }

    int og = w * 16 + (lane >> 4) * 4;             // lane's 4 output channels
    const f32x4 bias4 = *(const f32x4*)&fb[og];
    float sums[4] = {0.f, 0.f, 0.f, 0.f}, sqs[4] = {0.f, 0.f, 0.f, 0.f};
    #pragma unroll
    for (int j = 0; j < 2; ++j)
        #pragma unroll
        for (int ct = 0; ct < 4; ++ct) {
            int p = ct * 16 + (lane & 15);
            #pragma unroll
            for (int i = 0; i < 4; ++i) {
                int f = fs[j][i * 64 + p];
                if (f > 0) {
                    const f32x4 vc = *(const f32x4*)&zcorr[(size_t)(f - 1) * 64 + og];
                    acc[j][ct] += vc;
                }
            }
            acc[j][ct] += bias4;                   // z, kept in registers
            #pragma unroll
            for (int r = 0; r < 4; ++r) { sums[r] += acc[j][ct][r]; sqs[r] += acc[j][ct][r] * acc[j][ct][r]; }
        }
    #pragma unroll
    for (int r = 0; r < 4; ++r) {
        float s = sums[r], q = sqs[r];
        for (int m = 8; m >= 1; m >>= 1) {
            s += __shfl_xor(s, m);
            q += __shfl_xor(q, m);
        }
        if ((lane & 15) == 0) {
            pstats[(size_t)(og + r) * 512 + bid] = s;
            pstats[(size_t)(64 + og + r) * 512 + bid] = q;
        }
    }

    __threadfence();
    cg::this_grid().sync();

    // ---- phase 2: blocks 0-63 reduce channel bid ----
    if (bid < 64) {
        float s = 0.f, q = 0.f;
        #pragma unroll
        for (int rp = 0; rp < 2; ++rp) {
            s += pstats[(size_t)bid * 512 + rp * 256 + t];
            q += pstats[(size_t)(64 + bid) * 512 + rp * 256 + t];
        }
        #pragma unroll
        for (int m = 32; m >= 1; m >>= 1) {
            s += __shfl_xor(s, m);
            q += __shfl_xor(q, m);
        }
        if (lane == 0) { red_s[w] = s; red_q[w] = q; }
        __syncthreads();
        if (t == 0) {
            s = red_s[0] + red_s[1] + red_s[2] + red_s[3];
            q = red_q[0] + red_q[1] + red_q[2] + red_q[3];
            float cntf = (float)(B_ * (N_ + 2));
            float bias = fb[bid];
            s += 2.f * B_ * bias;                  // padded cols see bias only
            q += 2.f * B_ * bias * bias;
            float mean = s / cntf;
            float var = q / cntf - mean * mean;
            float scale = gamma[bid] / sqrtf(var + EPS);
            sc[bid] = scale;
            sc[64 + bid] = beta[bid] - mean * scale;
        }
    }

    __threadfence();
    cg::this_grid().sync();

    // ---- phase 3: BN + ReLU from registers -> out [B][O][N+2] ----
    const f32x4 scl4 = *(const f32x4*)&sc[og];
    const f32x4 sft4 = *(const f32x4*)&sc[64 + og];
    #pragma unroll
    for (int j = 0; j < 2; ++j)
        #pragma unroll
        for (int ct = 0; ct < 4; ++ct) {
            int n = base + j * 64 + ct * 16 + (lane & 15);
            #pragma unroll
            for (int r = 0; r < 4; ++r) {
                float v = fmaxf(acc[j][ct][r] * scl4[r] + sft4[r], 0.f);
                out[(size_t)(b * 64 + og + r) * (N_ + 2) + 1 + n] = v;
            }
        }
    if (bid == 64) {                               // pad columns (bias-only)
        int o = t & 63;
        float v = fmaxf(fb[o] * sc[o] + sc[64 + o], 0.f);
        out[(size_t)t * (N_ + 2)] = v;
        out[(size_t)t * (N_ + 2) + N_ + 1] = v;
    }
}

// ------------------------- fallback path (proven R5) -----------------------
__global__ __launch_bounds__(256) void k_fused_fb(
    const unsigned short* __restrict__ xtb, const int* __restrict__ h,
    const int* __restrict__ flag, const int* __restrict__ reidx,
    const unsigned short* __restrict__ Mfrag, const float* __restrict__ zcorr,
    const float* __restrict__ fb, float* __restrict__ zbuf,
    float* __restrict__ pstats)
{
    __shared__ __align__(16) unsigned short xg[256 * 64];
    __shared__ int fs[256];
    int bid = blockIdx.x;
    int b = (bid & 7) >> 1;
    int nb = ((bid >> 3) << 1) | (bid & 1);
    int n0 = nb * 64;
    int t = threadIdx.x;
    int lane = t & 63, w = t >> 6;

    int hvv[8];
    #pragma unroll
    for (int it = 0; it < 8; ++it)
        hvv[it] = h[(size_t)(w * 4 + b) * N_ + n0 + it * 8 + (lane >> 3)];
    short8 af[8];
    #pragma unroll
    for (int s = 0; s < 8; ++s)
        af[s] = *(const short8*)&Mfrag[(((size_t)w * 8 + s) * 64 + lane) * 8];
    #pragma unroll
    for (int it = 0; it < 8; ++it) {
        int p = it * 8 + (lane >> 3);
        int cg = (lane & 7) ^ (p & 7);
        const unsigned short* gp = xtb + ((size_t)b * N_ + hvv[it]) * 64 + cg * 8;
        gload16(gp, &xg[(size_t)(w * 64 + it * 8) * 64]);
    }
    {
        int i = t >> 6, p = t & 63;
        int pr = reidx[((size_t)b * N_ + n0 + p) * 4 + i];
        fs[t] = flag[(size_t)(i * 4 + b) * N_ + pr];
    }
    asm volatile("s_waitcnt vmcnt(0)" ::: "memory");
    __syncthreads();

    f32x4 acc[4];
    #pragma unroll
    for (int ct = 0; ct < 4; ++ct) { acc[ct][0]=0.f; acc[ct][1]=0.f; acc[ct][2]=0.f; acc[ct][3]=0.f; }
    #pragma unroll
    for (int s = 0; s < 8; ++s) {
        int i2 = s >> 1;
        int cg = (s & 1) * 4 + (lane >> 4);
        #pragma unroll
        for (int ct = 0; ct < 4; ++ct) {
            int pos = ct * 16 + (lane & 15);
            const short8 bf = *(const short8*)((const char*)xg +
                ((size_t)(i2 * 64 + pos) * 128) + ((cg ^ (pos & 7)) * 16));
            acc[ct] = __builtin_amdgcn_mfma_f32_16x16x32_bf16(af[s], bf, acc[ct], 0, 0, 0);
        }
    }

    int og = w * 16 + (lane >> 4) * 4;
    const f32x4 bias4 = *(const f32x4*)&fb[og];
    float sums[4] = {0.f, 0.f, 0.f, 0.f}, sqs[4] = {0.f, 0.f, 0.f, 0.f};
    #pragma unroll
    for (int ct = 0; ct < 4; ++ct) {
        int p = ct * 16 + (lane & 15);
        #pragma unroll
        for (int i = 0; i < 4; ++i) {
            int f = fs[i * 64 + p];
            if (f > 0) {
                const f32x4 vc = *(const f32x4*)&zcorr[(size_t)(f - 1) * 64 + og];
                acc[ct] += vc;
            }
        }
        f32x4 z = acc[ct] + bias4;
        int n = n0 + p;
        #pragma unroll
        for (int r = 0; r < 4; ++r) {
            zbuf[((size_t)b * O_ + og + r) * N_ + n] = z[r];
            sums[r] += z[r]; sqs[r] += z[r] * z[r];
        }
    }
    #pragma unroll
    for (int r = 0; r < 4; ++r) {
        float s = sums[r], q = sqs[r];
        for (int m = 8; m >= 1; m >>= 1) {
            s += __shfl_xor(s, m);
            q += __shfl_xor(q, m);
        }
        if ((lane & 15) == 0) {
            pstats[(size_t)(og + r) * 1024 + bid] = s;
            pstats[(size_t)(64 + og + r) * 1024 + bid] = q;
        }
    }
}

__global__ __launch_bounds__(256) void k_bnstats_fb(
    const float* __restrict__ pstats, const float* __restrict__ fb,
    const float* __restrict__ gamma, const float* __restrict__ beta,
    float* __restrict__ sc)
{
    __shared__ float ls[4], lq[4];
    int o = blockIdx.x, t = threadIdx.x;
    int lane = t & 63, w = t >> 6;
    float s = 0.f, q = 0.f;
    #pragma unroll
    for (int r = 0; r < 4; ++r) {
        s += pstats[(size_t)o * 1024 + r * 256 + t];
        q += pstats[(size_t)(64 + o) * 1024 + r * 256 + t];
    }
    #pragma unroll
    for (int m = 32; m >= 1; m >>= 1) {
        s += __shfl_xor(s, m);
        q += __shfl_xor(q, m);
    }
    if (lane == 0) { ls[w] = s; lq[w] = q; }
    __syncthreads();
    if (t == 0) {
        s = ls[0] + ls[1] + ls[2] + ls[3];
        q = lq[0] + lq[1] + lq[2] + lq[3];
        float cnt = (float)(B_ * (N_ + 2));
        float bias = fb[o];
        s += 2.f * B_ * bias;
        q += 2.f * B_ * bias * bias;
        float mean = s / cnt;
        float var = q / cnt - mean * mean;
        float scale = gamma[o] / sqrtf(var + EPS);
        sc[o] = scale;
        sc[O_ + o] = beta[o] - mean * scale;
    }
}

__global__ __launch_bounds__(256) void k_apply_fb(const float* __restrict__ zbuf,
                                                  const float* __restrict__ fb,
                                                  const float* __restrict__ sc,
                                                  float* __restrict__ out) {
    int bid = blockIdx.x, t = threadIdx.x;
    if (bid < 4096) {
        int gid = bid * 256 + t;
        int row = gid >> 12;
        int n = (gid & 4095) * 4;
        int o = row & 63;
        float scale = sc[o], shift = sc[O_ + o];
        f32x4 z = *(const f32x4*)&zbuf[(size_t)row * N_ + n];
        size_t ob = (size_t)row * (N_ + 2) + 1 + n;
        #pragma unroll
        for (int r = 0; r < 4; ++r)
            out[ob + r] = fmaxf(z[r] * scale + shift, 0.f);
    } else {
        int row = t;
        int o = row & 63;
        float v = fmaxf(fb[o] * sc[o] + sc[O_ + o], 0.f);
        out[(size_t)row * (N_ + 2)] = v;
        out[(size_t)row * (N_ + 2) + N_ + 1] = v;
    }
}

extern "C" void kernel_launch(void* const* d_in, const int* in_sizes, int n_in,
                              void* d_out, int out_size, void* d_ws, size_t ws_size,
                              hipStream_t stream) {
    const float* input   = (const float*)d_in[0];
    const float* mc      = (const float*)d_in[1];
    const int*   indices = (const int*)d_in[2];
    const int*   reidx   = (const int*)d_in[3];
    const float* cw      = (const float*)d_in[4];
    const float* fw      = (const float*)d_in[5];
    const float* fb      = (const float*)d_in[6];
    const float* gamma   = (const float*)d_in[7];
    const float* beta    = (const float*)d_in[8];
    float* out = (float*)d_out;

    char* ws = (char*)d_ws;
    size_t off = 0;
    auto alloc = [&](size_t bytes) { void* p = ws + off; off += (bytes + 255) & ~(size_t)255; return p; };
    unsigned short* xtb = (unsigned short*)alloc((size_t)B_ * N_ * C_ * 2);   // 8.4MB
    int*   h     = (int*)  alloc((size_t)4 * B_ * N_ * 4);                    // 1MB
    unsigned short* Mfrag = (unsigned short*)alloc((size_t)4 * 8 * 64 * 8 * 2);
    float* Wt    = (float*)alloc((size_t)4 * 9 * 4096 * 4);
    float* FWt   = (float*)alloc((size_t)4 * 4096 * 4);
    int*   emeta = (int*)  alloc((size_t)256 * RCAP * 4);
    float* ed    = (float*)alloc((size_t)256 * RCAP * 8 * 4);
    float* zcorr = (float*)alloc((size_t)256 * RCAP * 64 * 4);                // 8.4MB
    float* pstats= (float*)alloc((size_t)128 * 1024 * 4);                     // 512KB
    float* sc    = (float*)alloc((size_t)128 * 4);
    int*   flag  = (int*)  alloc((size_t)4 * B_ * N_ * 4);                    // 1MB
    int*   bcnt  = (int*)  alloc((size_t)256 * 4);
    float* zbuf  = (float*)alloc((size_t)B_ * O_ * N_ * 4);                   // 16.8MB (fallback only)

    k_setup<<<1580, 256, 0, stream>>>(input, mc, indices, reidx, cw, fw,
                                      xtb, h, Mfrag, Wt, FWt, flag, emeta, ed, bcnt);
    k_corr<<<2048, 64, 0, stream>>>(xtb, indices, Wt, FWt, emeta, ed, bcnt, zcorr);

    // gate the cooperative path on queried co-residency, then verify the launch
    bool coop = false;
    int maxb = 0;
    if (hipOccupancyMaxActiveBlocksPerMultiprocessor(
            &maxb, (const void*)k_mega2, 256, 0) == hipSuccess) {
        int dev = 0, cus = 0;
        hipGetDevice(&dev);
        hipDeviceGetAttribute(&cus, hipDeviceAttributeMultiprocessorCount, dev);
        if ((long)maxb * (long)cus >= 512) coop = true;
    }
    if (coop) {
        void* params[] = {(void*)&xtb, (void*)&h, (void*)&flag, (void*)&reidx,
                          (void*)&Mfrag, (void*)&zcorr, (void*)&fb, (void*)&gamma,
                          (void*)&beta, (void*)&pstats, (void*)&sc, (void*)&out};
        if (hipLaunchCooperativeKernel((const void*)k_mega2, dim3(512), dim3(256),
                                       params, 0, stream) != hipSuccess)
            coop = false;
    }
    if (!coop) {
        k_fused_fb<<<1024, 256, 0, stream>>>(xtb, h, flag, reidx, Mfrag, zcorr,
                                             fb, zbuf, pstats);
        k_bnstats_fb<<<64, 256, 0, stream>>>(pstats, fb, gamma, beta, sc);
        k_apply_fb<<<4097, 256, 0, stream>>>(zbuf, fb, sc, out);
    }
}

// Round 8
// 57.451 us; speedup vs baseline: 4.5753x; 4.5753x over previous
//
#include <hip/hip_runtime.h>

#define K_ 9
#define SIGMA_INV 12.5f
#define EPS 1e-5f
#define B_ 4
#define C_ 64
#define O_ 64
#define N_ 16384
#define RCAP 128      // per-region correction-entry capacity (256 regions)

typedef __attribute__((ext_vector_type(8))) short short8;
typedef __attribute__((ext_vector_type(8))) unsigned short ushort8;
typedef __attribute__((ext_vector_type(4))) float f32x4;

__device__ __forceinline__ unsigned short f2bf(float f) {
    union { float f; unsigned u; } v; v.f = f;
    unsigned r = v.u + 0x7fffu + ((v.u >> 16) & 1u);   // round-nearest-even
    return (unsigned short)(r >> 16);
}
__device__ __forceinline__ float bf2f(unsigned short h) {
    union { unsigned u; float f; } v; v.u = ((unsigned)h) << 16;
    return v.f;
}
__device__ __forceinline__ void gload16(const void* g, void* l) {
    __builtin_amdgcn_global_load_lds((const __attribute__((address_space(1))) unsigned int*)g,
                                     (__attribute__((address_space(3))) unsigned int*)l,
                                     16, 0, 0);
}

// ---------------------------------------------------------------------------
// K_setup: heterogeneous roles, one launch.
//  [0,1024)      : transpose+bf16-convert tile (64n x 64c)
//  [1024,1280)   : scan (region-compacted via LDS atomic; flag/bcnt written
//                  unconditionally -> zero memsets needed)
//  [1280,1324)   : prep (4x M->Mfrag, 36x Wt, 4x FWt)
//  [1324,1580)   : chain: h[i][b][n] = composed-gather(reidx), pointer-chase
// ---------------------------------------------------------------------------
__global__ __launch_bounds__(256) void k_setup(
    const float* __restrict__ in, const float* __restrict__ mc,
    const int* __restrict__ indices, const int* __restrict__ reidx,
    const float* __restrict__ cw, const float* __restrict__ fw,
    unsigned short* __restrict__ xtb, int* __restrict__ h,
    unsigned short* __restrict__ Mfrag, float* __restrict__ Wt,
    float* __restrict__ FWt,
    int* __restrict__ flag, int* __restrict__ emeta,
    float* __restrict__ ed, int* __restrict__ bcnt)
{
    int bid = blockIdx.x, t = threadIdx.x;
    if (bid < 1024) {                                    // ---- transpose + cvt
        __shared__ float tile[64][65];
        int b = bid & 3, n0 = (bid >> 2) * 64;
        for (int rep = 0; rep < 16; ++rep) {
            int idx = rep * 256 + t;
            int c = idx >> 6, j = idx & 63;
            tile[c][j] = in[((size_t)b * C_ + c) * N_ + n0 + j];
        }
        __syncthreads();
        for (int rep = 0; rep < 4; ++rep) {              // ushort4 packed writes
            int idx = rep * 256 + t;
            int j = idx >> 4, c4 = (idx & 15) * 4;
            ushort4 o;
            o.x = f2bf(tile[c4 + 0][j]); o.y = f2bf(tile[c4 + 1][j]);
            o.z = f2bf(tile[c4 + 2][j]); o.w = f2bf(tile[c4 + 3][j]);
            *(ushort4*)&xtb[((size_t)b * N_ + n0 + j) * 64 + c4] = o;
        }
    } else if (bid < 1280) {                             // ---- scan
        __shared__ float cs[3][264][4];
        __shared__ int lcnt;
        int sb = bid - 1024;                             // region id
        int b = sb & 3, n0 = (sb >> 2) * 256;
        if (t == 0) lcnt = 0;
        for (int idx = t; idx < 3 * 264; idx += 256) {
            int a = idx / 264, r = idx - a * 264;
            int m = n0 + r - 4;
            f32x4 v;
            if (m >= 0 && m < N_) v = *(const f32x4*)&mc[(((size_t)b * 3 + a) * N_ + m) * 4];
            else { v[0] = 1e9f; v[1] = 1e9f; v[2] = 1e9f; v[3] = 1e9f; }
            *(f32x4*)&cs[a][r][0] = v;
        }
        __syncthreads();
        int p = n0 + t;
        for (int i = 0; i < 4; ++i) {
            float c0 = cs[0][t + 4][i], c1 = cs[1][t + 4][i], c2 = cs[2][t + 4][i];
            float d[8]; bool any = false;
            #pragma unroll
            for (int kk = 0; kk < 8; ++kk) {
                int k = kk + (kk >= 4);
                float d0 = cs[0][t + k][i] - c0, d1 = cs[1][t + k][i] - c1,
                      d2 = cs[2][t + k][i] - c2;
                float dist = sqrtf(d0 * d0 + d1 * d1 + d2 * d2);
                float dd = 1.f - dist * SIGMA_INV;
                d[kk] = dd > 0.f ? dd : 0.f;
                any = any || (dd > 0.f);
            }
            int fv = 0;
            if (any) {
                int li = atomicAdd(&lcnt, 1);            // LDS atomic: no global init
                if (li < RCAP) {
                    int slot = sb * RCAP + li;
                    emeta[slot] = (i << 14) | p;
                    #pragma unroll
                    for (int kk = 0; kk < 8; ++kk) ed[(size_t)slot * 8 + kk] = d[kk];
                    fv = slot + 1;
                }
            }
            flag[(size_t)(i * 4 + b) * N_ + p] = fv;     // unconditional
        }
        __syncthreads();
        if (t == 0) bcnt[sb] = lcnt < RCAP ? lcnt : RCAP;
    } else if (bid < 1324) {                             // ---- prep
        int pb = bid - 1280;
        if (pb < 4) {
            __shared__ float w4[64][65];
            __shared__ float fws[64][65];
            int i = pb;
            for (int idx = t; idx < 4096; idx += 256) {
                int op = idx >> 6, c = idx & 63;
                w4[op][c]  = cw[(((size_t)(i * 64 + op)) * 64 + c) * 9 + 4];
                fws[op][c] = fw[(size_t)op * 256 + i * 64 + c];
            }
            __syncthreads();
            int o = t >> 2, cb = (t & 3) * 16;
            float acc[16];
            #pragma unroll
            for (int j = 0; j < 16; ++j) acc[j] = 0.f;
            for (int op = 0; op < 64; ++op) {
                float f = fws[o][op];
                #pragma unroll
                for (int j = 0; j < 16; ++j) acc[j] += f * w4[op][cb + j];
            }
            // MFMA A-fragment layout: Mfrag[w][s][lane][8]
            #pragma unroll
            for (int j = 0; j < 16; ++j) {
                int c = cb + j;
                int s = i * 2 + (c >> 5);
                int l = (((c >> 3) & 3) << 4) | (o & 15);
                int w_ = o >> 4;
                Mfrag[(((size_t)w_ * 8 + s) * 64 + l) * 8 + (c & 7)] = f2bf(acc[j]);
            }
        } else if (pb < 40) {
            int idx2 = pb - 4;
            int i = idx2 / 9, k = idx2 - i * 9;
            for (int idx = t; idx < 4096; idx += 256) {
                int c = idx >> 6, o = idx & 63;
                Wt[(size_t)(i * 9 + k) * 4096 + c * 64 + o] =
                    cw[(((size_t)(i * 64 + o)) * 64 + c) * 9 + k];
            }
        } else {
            int i = pb - 40;
            for (int idx = t; idx < 4096; idx += 256) {
                int c = idx >> 6, o = idx & 63;
                FWt[(size_t)(i * 64 + c) * 64 + o] = fw[(size_t)o * 256 + i * 64 + c];
            }
        }
    } else {                                             // ---- chain
        int gid = (bid - 1324) * 256 + t;                // over B*N
        int b = gid >> 14, n = gid & (N_ - 1);
        const int* ib = indices + (size_t)b * N_ * 4;
        const int4 r = *(const int4*)&reidx[((size_t)b * N_ + n) * 4];
        int t0 = ib[(size_t)r.x * 4 + 0];
        int t1 = ib[(size_t)r.y * 4 + 1];
        int t2 = ib[(size_t)r.z * 4 + 2];
        int t3 = ib[(size_t)r.w * 4 + 3];
        t1 = ib[(size_t)t1 * 4 + 0];
        t2 = ib[(size_t)t2 * 4 + 1];
        t3 = ib[(size_t)t3 * 4 + 2];
        t2 = ib[(size_t)t2 * 4 + 0];
        t3 = ib[(size_t)t3 * 4 + 1];
        t3 = ib[(size_t)t3 * 4 + 0];
        h[(size_t)(0 * 4 + b) * N_ + n] = t0;
        h[(size_t)(1 * 4 + b) * N_ + n] = t1;
        h[(size_t)(2 * 4 + b) * N_ + n] = t2;
        h[(size_t)(3 * 4 + b) * N_ + n] = t3;
    }
}

// corrections: region-sliced; wave (bid&7) of region (bid>>3) handles entries
// li = wir, wir+8, ... ; tap rows pointer-chased in parallel lanes.
__global__ __launch_bounds__(64) void k_corr(
    const unsigned short* __restrict__ xtb, const int* __restrict__ indices,
    const float* __restrict__ Wt, const float* __restrict__ FWt,
    const int* __restrict__ emeta, const float* __restrict__ ed,
    const int* __restrict__ bcnt, float* __restrict__ zcorr)
{
    __shared__ float xls[8][64];
    __shared__ float ycs[64];
    __shared__ int rows_s[8];
    int t = threadIdx.x;
    int r = blockIdx.x >> 3, wir = blockIdx.x & 7;
    int b = r & 3;
    int cr = bcnt[r];
    const int* idxb = indices + (size_t)b * N_ * 4;
    for (int li = wir; li < cr; li += 8) {
        int slot = r * RCAP + li;
        int meta = emeta[slot];
        int i = meta >> 14, p = meta & 16383;
        float dd[8];
        #pragma unroll
        for (int kk = 0; kk < 8; ++kk) dd[kk] = ed[(size_t)slot * 8 + kk];
        if (t < 8) {                         // lane t chases tap t's row
            int row = 0;
            if (dd[t] > 0.f) {
                int k = t + (t >= 4);
                int rr = p + k - 4;          // in-bounds guaranteed when dd>0
                for (int s = i; s >= 0; --s) rr = idxb[(size_t)rr * 4 + s];
                row = rr;
            }
            rows_s[t] = row;
        }
        __syncthreads();
        #pragma unroll
        for (int kk = 0; kk < 8; ++kk) {
            if (dd[kk] > 0.f)
                xls[kk][t] = bf2f(xtb[((size_t)b * N_ + rows_s[kk]) * 64 + t]);
        }
        __syncthreads();
        float y = 0.f;
        #pragma unroll 1
        for (int kk = 0; kk < 8; ++kk) {
            if (dd[kk] > 0.f) {
                int k = kk + (kk >= 4);
                const float* w = Wt + (size_t)(i * 9 + k) * 4096;
                float s0 = 0.f, s1 = 0.f, s2 = 0.f, s3 = 0.f;
                #pragma unroll
                for (int c = 0; c < 64; c += 4) {
                    s0 += w[(c + 0) * 64 + t] * xls[kk][c + 0];
                    s1 += w[(c + 1) * 64 + t] * xls[kk][c + 1];
                    s2 += w[(c + 2) * 64 + t] * xls[kk][c + 2];
                    s3 += w[(c + 3) * 64 + t] * xls[kk][c + 3];
                }
                y += dd[kk] * (((s0 + s1) + (s2 + s3)));
            }
        }
        ycs[t] = y;
        __syncthreads();
        const float* fwt = FWt + (size_t)i * 4096;
        float v0 = 0.f, v1 = 0.f, v2 = 0.f, v3 = 0.f;
        #pragma unroll
        for (int c = 0; c < 64; c += 4) {
            v0 += fwt[(c + 0) * 64 + t] * ycs[c + 0];
            v1 += fwt[(c + 1) * 64 + t] * ycs[c + 1];
            v2 += fwt[(c + 2) * 64 + t] * ycs[c + 2];
            v3 += fwt[(c + 3) * 64 + t] * ycs[c + 3];
        }
        zcorr[(size_t)slot * 64 + t] = (v0 + v1) + (v2 + v3);
        __syncthreads();
    }
}

// ---------------------------------------------------------------------------
// k_fused: Z[64o x 64pos] = concat_i(M_i)[64x256] . stack_i(gather_i)[256x64]
// via mfma_f32_16x16x32_bf16. BN partials from fp32 registers; z stored bf16.
// ---------------------------------------------------------------------------
__global__ __launch_bounds__(256) void k_fused(
    const unsigned short* __restrict__ xtb, const int* __restrict__ h,
    const int* __restrict__ flag, const int* __restrict__ reidx,
    const unsigned short* __restrict__ Mfrag, const float* __restrict__ zcorr,
    const float* __restrict__ fb, unsigned short* __restrict__ zbuf,
    float* __restrict__ pstats)
{
    __shared__ __align__(16) unsigned short xg[256 * 64];   // bf16, chunk-swizzled
    __shared__ int fs[256];
    int bid = blockIdx.x;
    int b = (bid & 7) >> 1;                        // batch -> XCD pair (L2 locality)
    int nb = ((bid >> 3) << 1) | (bid & 1);
    int n0 = nb * 64;
    int t = threadIdx.x;
    int lane = t & 63, w = t >> 6;

    int hvv[8];
    #pragma unroll
    for (int it = 0; it < 8; ++it)
        hvv[it] = h[(size_t)(w * 4 + b) * N_ + n0 + it * 8 + (lane >> 3)];
    short8 af[8];
    #pragma unroll
    for (int s = 0; s < 8; ++s)
        af[s] = *(const short8*)&Mfrag[(((size_t)w * 8 + s) * 64 + lane) * 8];
    #pragma unroll
    for (int it = 0; it < 8; ++it) {
        int p = it * 8 + (lane >> 3);
        int cg = (lane & 7) ^ (p & 7);             // source-chunk swizzle
        const unsigned short* gp = xtb + ((size_t)b * N_ + hvv[it]) * 64 + cg * 8;
        gload16(gp, &xg[(size_t)(w * 64 + it * 8) * 64]);
    }
    {   // correction flags: dependent chain overlapped with gather latency
        int i = t >> 6, p = t & 63;
        int pr = reidx[((size_t)b * N_ + n0 + p) * 4 + i];
        fs[t] = flag[(size_t)(i * 4 + b) * N_ + pr];
    }
    asm volatile("s_waitcnt vmcnt(0)" ::: "memory");
    __syncthreads();

    f32x4 acc[4];
    #pragma unroll
    for (int ct = 0; ct < 4; ++ct) { acc[ct][0]=0.f; acc[ct][1]=0.f; acc[ct][2]=0.f; acc[ct][3]=0.f; }
    #pragma unroll
    for (int s = 0; s < 8; ++s) {
        int i2 = s >> 1;
        int cg = (s & 1) * 4 + (lane >> 4);
        #pragma unroll
        for (int ct = 0; ct < 4; ++ct) {
            int pos = ct * 16 + (lane & 15);
            const short8 bf = *(const short8*)((const char*)xg +
                ((size_t)(i2 * 64 + pos) * 128) + ((cg ^ (pos & 7)) * 16));
            acc[ct] = __builtin_amdgcn_mfma_f32_16x16x32_bf16(af[s], bf, acc[ct], 0, 0, 0);
        }
    }

    int og = w * 16 + (lane >> 4) * 4;             // lane's 4 output channels
    const f32x4 bias4 = *(const f32x4*)&fb[og];
    float sums[4] = {0.f, 0.f, 0.f, 0.f}, sqs[4] = {0.f, 0.f, 0.f, 0.f};
    #pragma unroll
    for (int ct = 0; ct < 4; ++ct) {
        int p = ct * 16 + (lane & 15);
        #pragma unroll
        for (int i = 0; i < 4; ++i) {
            int f = fs[i * 64 + p];
            if (f > 0) {
                const f32x4 vc = *(const f32x4*)&zcorr[(size_t)(f - 1) * 64 + og];
                acc[ct] += vc;
            }
        }
        f32x4 z = acc[ct] + bias4;
        int n = n0 + p;
        #pragma unroll
        for (int r = 0; r < 4; ++r) {
            zbuf[((size_t)b * O_ + og + r) * N_ + n] = f2bf(z[r]);
            sums[r] += z[r]; sqs[r] += z[r] * z[r];
        }
    }
    #pragma unroll
    for (int r = 0; r < 4; ++r) {
        float s = sums[r], q = sqs[r];
        for (int m = 8; m >= 1; m >>= 1) {
            s += __shfl_xor(s, m);
            q += __shfl_xor(q, m);
        }
        if ((lane & 15) == 0) {
            pstats[(size_t)(og + r) * 1024 + bid] = s;
            pstats[(size_t)(64 + og + r) * 1024 + bid] = q;
        }
    }
}

// 64 blocks, one per channel: reduce pstats -> scale/shift; write pad columns.
__global__ __launch_bounds__(256) void k_bnstats(
    const float* __restrict__ pstats, const float* __restrict__ fb,
    const float* __restrict__ gamma, const float* __restrict__ beta,
    float* __restrict__ sc, float* __restrict__ out)
{
    __shared__ float ls[4], lq[4];
    int o = blockIdx.x, t = threadIdx.x;
    int lane = t & 63, w = t >> 6;
    float s = 0.f, q = 0.f;
    #pragma unroll
    for (int r = 0; r < 4; ++r) {
        s += pstats[(size_t)o * 1024 + r * 256 + t];
        q += pstats[(size_t)(64 + o) * 1024 + r * 256 + t];
    }
    #pragma unroll
    for (int m = 32; m >= 1; m >>= 1) {
        s += __shfl_xor(s, m);
        q += __shfl_xor(q, m);
    }
    if (lane == 0) { ls[w] = s; lq[w] = q; }
    __syncthreads();
    if (t == 0) {
        s = ls[0] + ls[1] + ls[2] + ls[3];
        q = lq[0] + lq[1] + lq[2] + lq[3];
        float cnt = (float)(B_ * (N_ + 2));
        float bias = fb[o];
        s += 2.f * B_ * bias;                      // padded cols see bias only
        q += 2.f * B_ * bias * bias;
        float mean = s / cnt;
        float var = q / cnt - mean * mean;
        float scale = gamma[o] / sqrtf(var + EPS);
        sc[o] = scale;
        sc[O_ + o] = beta[o] - mean * scale;
        float pv = fmaxf(bias * scale + (beta[o] - mean * scale), 0.f);
        #pragma unroll
        for (int b = 0; b < B_; ++b) {             // pad columns
            out[(size_t)(b * O_ + o) * (N_ + 2)] = pv;
            out[(size_t)(b * O_ + o) * (N_ + 2) + N_ + 1] = pv;
        }
    }
}

// BN + ReLU from bf16 zbuf -> out [B][O][N+2] interior; 2048 blocks x 8 elems
__global__ __launch_bounds__(256) void k_apply(const unsigned short* __restrict__ zbuf,
                                               const float* __restrict__ sc,
                                               float* __restrict__ out) {
    int gid = blockIdx.x * 256 + threadIdx.x;
    int row = gid >> 11;                           // (b*64+o), 2048 chunks of 8
    int n = (gid & 2047) * 8;
    int o = row & 63;
    float scale = sc[o], shift = sc[O_ + o];
    ushort8 z = *(const ushort8*)&zbuf[(size_t)row * N_ + n];
    size_t ob = (size_t)row * (N_ + 2) + 1 + n;
    #pragma unroll
    for (int r = 0; r < 8; ++r)
        out[ob + r] = fmaxf(bf2f(z[r]) * scale + shift, 0.f);
}

extern "C" void kernel_launch(void* const* d_in, const int* in_sizes, int n_in,
                              void* d_out, int out_size, void* d_ws, size_t ws_size,
                              hipStream_t stream) {
    const float* input   = (const float*)d_in[0];
    const float* mc      = (const float*)d_in[1];
    const int*   indices = (const int*)d_in[2];
    const int*   reidx   = (const int*)d_in[3];
    const float* cw      = (const float*)d_in[4];
    const float* fw      = (const float*)d_in[5];
    const float* fb      = (const float*)d_in[6];
    const float* gamma   = (const float*)d_in[7];
    const float* beta    = (const float*)d_in[8];
    float* out = (float*)d_out;

    char* ws = (char*)d_ws;
    size_t off = 0;
    auto alloc = [&](size_t bytes) { void* p = ws + off; off += (bytes + 255) & ~(size_t)255; return p; };
    unsigned short* xtb = (unsigned short*)alloc((size_t)B_ * N_ * C_ * 2);   // 8.4MB
    int*   h     = (int*)  alloc((size_t)4 * B_ * N_ * 4);                    // 1MB
    unsigned short* Mfrag = (unsigned short*)alloc((size_t)4 * 8 * 64 * 8 * 2);
    float* Wt    = (float*)alloc((size_t)4 * 9 * 4096 * 4);
    float* FWt   = (float*)alloc((size_t)4 * 4096 * 4);
    int*   emeta = (int*)  alloc((size_t)256 * RCAP * 4);
    float* ed    = (float*)alloc((size_t)256 * RCAP * 8 * 4);
    float* zcorr = (float*)alloc((size_t)256 * RCAP * 64 * 4);                // 8.4MB
    float* pstats= (float*)alloc((size_t)128 * 1024 * 4);                     // 512KB
    float* sc    = (float*)alloc((size_t)128 * 4);
    int*   flag  = (int*)  alloc((size_t)4 * B_ * N_ * 4);                    // 1MB
    int*   bcnt  = (int*)  alloc((size_t)256 * 4);
    unsigned short* zbuf = (unsigned short*)alloc((size_t)B_ * O_ * N_ * 2);  // 8.4MB bf16

    k_setup<<<1580, 256, 0, stream>>>(input, mc, indices, reidx, cw, fw,
                                      xtb, h, Mfrag, Wt, FWt, flag, emeta, ed, bcnt);
    k_corr<<<2048, 64, 0, stream>>>(xtb, indices, Wt, FWt, emeta, ed, bcnt, zcorr);
    k_fused<<<1024, 256, 0, stream>>>(xtb, h, flag, reidx, Mfrag, zcorr,
                                      fb, zbuf, pstats);
    k_bnstats<<<64, 256, 0, stream>>>(pstats, fb, gamma, beta, sc, out);
    k_apply<<<2048, 256, 0, stream>>>(zbuf, sc, out);
}